// Round 6
// baseline (340.955 us; speedup 1.0000x reference)
//
#include <hip/hip_runtime.h>
#include <math.h>

#define B_N 16384
#define C_N 250
#define D_N 2048
#define CP  256

// ---- workspace layout (float offsets) ----
// zeroed region (one small hipMemsetAsync):
#define OFF_PP     0          // 62500
#define OFF_SCAL   62500      // 64 (incl tail counter u[8])
#define OFF_C2RAW  62564      // 256 (gram diag atomicAdd target)
#define ZERO_N     62820
// non-zeroed (fully written before read):
#define OFF_COUNTS 62820      // 256
#define OFF_OFFG   63076      // 260 ints (off[257])
#define OFF_BH     63336      // 16384 ints
#define OFF_SORT   79720      // 16384 ints
#define OFF_CENT   96104      // 524288 (mean, fp32)
#define OFF_GRAMP  620392     // 1048576 = 16 slices x 256x256
#define OFF_PSN    1668968    // 65536 = 4 quarters x 16384
#define OFF_CENTNB 1734504    // 262144 floats = 256x2048 bf16 (UNnormalized mean)
#define T1_END     1996648    // ~8 MB
#define OFF_EBF    1996648    // 16777216 floats = 16384x2048 bf16 (UNnormalized)
#define T2_END     18773864   // ~75 MB

// scalar slots: float: 0=ce_sum 1=S1(pd^2) 2=margin_sum 5=n_upper 6=n_pairs
//               9=S2(pd*M) 10=S3(M^2) 11=npresent(float)
// uint: 3=maxM bits, 4=pmax bits, 8=tail counter

typedef __bf16 bf16x8 __attribute__((ext_vector_type(8)));
typedef float  f32x4  __attribute__((ext_vector_type(4)));

__device__ __forceinline__ unsigned short bfbits(float x){
  unsigned u = __float_as_uint(x);
  return (unsigned short)((u + 0x7FFFu + ((u>>16)&1u)) >> 16);  // RNE
}

__device__ __forceinline__ void gload_lds16(const void* g, void* l){
  __builtin_amdgcn_global_load_lds(
      (const __attribute__((address_space(1))) unsigned*)g,
      (__attribute__((address_space(3))) unsigned*)l, 16, 0, 0);
}

__device__ __forceinline__ float warpSum(float v){
#pragma unroll
  for(int o=32;o;o>>=1) v += __shfl_xor(v,o,64);
  return v;
}
__device__ __forceinline__ float warpMax(float v){
#pragma unroll
  for(int o=32;o;o>>=1) v = fmaxf(v, __shfl_xor(v,o,64));
  return v;
}
__device__ __forceinline__ float blockSum256(float v){
  __shared__ float s[4];
  int lane = threadIdx.x & 63, w = threadIdx.x >> 6;
  v = warpSum(v);
  __syncthreads();
  if(lane==0) s[w]=v;
  __syncthreads();
  return s[0]+s[1]+s[2]+s[3];
}
__device__ __forceinline__ float blockMax256(float v){
  __shared__ float s[4];
  int lane = threadIdx.x & 63, w = threadIdx.x >> 6;
  v = warpMax(v);
  __syncthreads();
  if(lane==0) s[w]=v;
  __syncthreads();
  return fmaxf(fmaxf(s[0],s[1]), fmaxf(s[2],s[3]));
}

// ---------------- fat1: CE (blocks 0..1023) + hist+maxM+pad (1024..1087) ----
__global__ __launch_bounds__(256) void tgl_cehist(const float* __restrict__ logits,
                                                  const int* __restrict__ labels,
                                                  const float* __restrict__ M,
                                                  int* __restrict__ bh,
                                                  unsigned short* __restrict__ centnb,
                                                  float* __restrict__ scal){
  if(blockIdx.x >= 1024){
    __shared__ int h[256];
    unsigned* scal_u = (unsigned*)scal;
    int b = blockIdx.x - 1024, t = threadIdx.x;
    h[t] = 0;
    __syncthreads();
    atomicAdd(&h[labels[b*256 + t]], 1);
    __syncthreads();
    bh[b*256 + t] = h[t];
    // fused max(M) chunk (needed by tail2's margin mask)
    float lm = 0.f;
    int i1 = b*977 + 977; if(i1 > C_N*C_N) i1 = C_N*C_N;
    for(int i = b*977 + t; i < i1; i += 256) lm = fmaxf(lm, M[i]);
    lm = blockMax256(lm);
    if(t==0) atomicMax(&scal_u[3], __float_as_uint(lm));
    // centnb bf16 zero-pad rows 250..255 (margin B-staging reads 256 rows)
    if(b < 6){
      for(int d=t; d<D_N; d+=256) centnb[(size_t)(C_N+b)*D_N + d] = 0;
    }
    return;
  }
  int lane = threadIdx.x & 63, w = threadIdx.x >> 6;
  float lsum = 0.f;
#pragma unroll
  for(int u=0; u<4; ++u){
    int r = blockIdx.x*16 + w*4 + u;
    const float* row = logits + (size_t)r*C_N;
    float x0 = (lane     < C_N) ? row[lane]     : -1e30f;
    float x1 = (lane+64  < C_N) ? row[lane+64]  : -1e30f;
    float x2 = (lane+128 < C_N) ? row[lane+128] : -1e30f;
    float x3 = (lane+192 < C_N) ? row[lane+192] : -1e30f;
    float mx = warpMax(fmaxf(fmaxf(x0,x1), fmaxf(x2,x3)));
    float e = 0.f;
    if(lane     < C_N) e += expf(x0-mx);
    if(lane+64  < C_N) e += expf(x1-mx);
    if(lane+128 < C_N) e += expf(x2-mx);
    if(lane+192 < C_N) e += expf(x3-mx);
    e = warpSum(e);
    if(lane==0){
      int l = labels[r];
      lsum += -(row[l] - mx - logf(e));
    }
  }
  float tot = blockSum256(lsum);
  if(threadIdx.x==0) atomicAdd(&scal[0], tot);
}

// ---------------- scatter2: per-block re-scan of bh + scatter (scan fused) --
__global__ __launch_bounds__(256) void tgl_scatter(const int* __restrict__ labels,
                                                   const int* __restrict__ bh,
                                                   int* __restrict__ offg,
                                                   float* __restrict__ counts,
                                                   int* __restrict__ sorted){
  __shared__ int ps[256];
  __shared__ int lofs[256];
  int t = threadIdx.x, b = blockIdx.x;
  int run = 0, locb = 0;
#pragma unroll
  for(int b2=0;b2<64;b2++){
    int h = bh[b2*256 + t];
    if(b2 < b) locb += h;
    run += h;
  }
  ps[t] = run;
  __syncthreads();
  for(int o=1;o<256;o<<=1){
    int v = (t>=o) ? ps[t-o] : 0;
    __syncthreads();
    ps[t] += v;
    __syncthreads();
  }
  int excl = ps[t] - run;
  if(b==0){
    offg[t] = excl;
    if(t==255) offg[256] = ps[255];
    counts[t] = (float)run;
  }
  lofs[t] = excl + locb;
  __syncthreads();
  int r = b*256 + t;
  int pos = atomicAdd(&lofs[labels[r]], 1);
  sorted[pos] = r;
}

// ---------------- gather: segment sum, 4-row MLP; epilogue writes mean+bf16 --
template<bool EBF>
__global__ __launch_bounds__(256) void tgl_gather(const float* __restrict__ emb,
                                                  const int* __restrict__ sorted,
                                                  const int* __restrict__ offg,
                                                  float* __restrict__ cent,
                                                  float* __restrict__ psn,
                                                  unsigned short* __restrict__ ebf,
                                                  unsigned short* __restrict__ centnb){
  __shared__ float red[2048];            // 8 KB
  int t = threadIdx.x, l = t & 63, w = t >> 6;
  int c = blockIdx.x, h = blockIdx.y;
  int d0 = h*512;
  int off = offg[c];
  int cnt = offg[c+1] - off;
  const int* rows = sorted + off;
  f32x4 acc0 = {}, acc1 = {};
  int k = w;
  for(; k+12 < cnt; k += 16){
    int r0 = rows[k], r1 = rows[k+4], r2 = rows[k+8], r3 = rows[k+12];
    const float* p0 = emb + (size_t)r0*D_N + d0;
    const float* p1 = emb + (size_t)r1*D_N + d0;
    const float* p2 = emb + (size_t)r2*D_N + d0;
    const float* p3 = emb + (size_t)r3*D_N + d0;
    float4 a0 = *(const float4*)&p0[l*4];
    float4 a1 = *(const float4*)&p0[256 + l*4];
    float4 b0 = *(const float4*)&p1[l*4];
    float4 b1 = *(const float4*)&p1[256 + l*4];
    float4 c0 = *(const float4*)&p2[l*4];
    float4 c1 = *(const float4*)&p2[256 + l*4];
    float4 e0 = *(const float4*)&p3[l*4];
    float4 e1 = *(const float4*)&p3[256 + l*4];
    float sq0 = a0.x*a0.x+a0.y*a0.y+a0.z*a0.z+a0.w*a0.w
              + a1.x*a1.x+a1.y*a1.y+a1.z*a1.z+a1.w*a1.w;
    float sq1 = b0.x*b0.x+b0.y*b0.y+b0.z*b0.z+b0.w*b0.w
              + b1.x*b1.x+b1.y*b1.y+b1.z*b1.z+b1.w*b1.w;
    float sq2 = c0.x*c0.x+c0.y*c0.y+c0.z*c0.z+c0.w*c0.w
              + c1.x*c1.x+c1.y*c1.y+c1.z*c1.z+c1.w*c1.w;
    float sq3 = e0.x*e0.x+e0.y*e0.y+e0.z*e0.z+e0.w*e0.w
              + e1.x*e1.x+e1.y*e1.y+e1.z*e1.z+e1.w*e1.w;
    sq0 = warpSum(sq0); sq1 = warpSum(sq1); sq2 = warpSum(sq2); sq3 = warpSum(sq3);
    if(l==0){
      psn[(size_t)h*B_N + r0] = sq0;
      psn[(size_t)h*B_N + r1] = sq1;
      psn[(size_t)h*B_N + r2] = sq2;
      psn[(size_t)h*B_N + r3] = sq3;
    }
    if constexpr(EBF){
      unsigned short* o0 = ebf + (size_t)r0*D_N + d0;
      unsigned short* o1 = ebf + (size_t)r1*D_N + d0;
      unsigned short* o2 = ebf + (size_t)r2*D_N + d0;
      unsigned short* o3 = ebf + (size_t)r3*D_N + d0;
      ushort4 hb;
      hb.x=bfbits(a0.x); hb.y=bfbits(a0.y); hb.z=bfbits(a0.z); hb.w=bfbits(a0.w);
      *(ushort4*)&o0[l*4] = hb;
      hb.x=bfbits(a1.x); hb.y=bfbits(a1.y); hb.z=bfbits(a1.z); hb.w=bfbits(a1.w);
      *(ushort4*)&o0[256 + l*4] = hb;
      hb.x=bfbits(b0.x); hb.y=bfbits(b0.y); hb.z=bfbits(b0.z); hb.w=bfbits(b0.w);
      *(ushort4*)&o1[l*4] = hb;
      hb.x=bfbits(b1.x); hb.y=bfbits(b1.y); hb.z=bfbits(b1.z); hb.w=bfbits(b1.w);
      *(ushort4*)&o1[256 + l*4] = hb;
      hb.x=bfbits(c0.x); hb.y=bfbits(c0.y); hb.z=bfbits(c0.z); hb.w=bfbits(c0.w);
      *(ushort4*)&o2[l*4] = hb;
      hb.x=bfbits(c1.x); hb.y=bfbits(c1.y); hb.z=bfbits(c1.z); hb.w=bfbits(c1.w);
      *(ushort4*)&o2[256 + l*4] = hb;
      hb.x=bfbits(e0.x); hb.y=bfbits(e0.y); hb.z=bfbits(e0.z); hb.w=bfbits(e0.w);
      *(ushort4*)&o3[l*4] = hb;
      hb.x=bfbits(e1.x); hb.y=bfbits(e1.y); hb.z=bfbits(e1.z); hb.w=bfbits(e1.w);
      *(ushort4*)&o3[256 + l*4] = hb;
    }
    acc0[0]+=a0.x+b0.x+c0.x+e0.x; acc0[1]+=a0.y+b0.y+c0.y+e0.y;
    acc0[2]+=a0.z+b0.z+c0.z+e0.z; acc0[3]+=a0.w+b0.w+c0.w+e0.w;
    acc1[0]+=a1.x+b1.x+c1.x+e1.x; acc1[1]+=a1.y+b1.y+c1.y+e1.y;
    acc1[2]+=a1.z+b1.z+c1.z+e1.z; acc1[3]+=a1.w+b1.w+c1.w+e1.w;
  }
  for(; k < cnt; k += 4){
    int r0 = rows[k];
    const float* p0 = emb + (size_t)r0*D_N + d0;
    float4 a0 = *(const float4*)&p0[l*4];
    float4 a1 = *(const float4*)&p0[256 + l*4];
    float sq0 = a0.x*a0.x+a0.y*a0.y+a0.z*a0.z+a0.w*a0.w
              + a1.x*a1.x+a1.y*a1.y+a1.z*a1.z+a1.w*a1.w;
    sq0 = warpSum(sq0);
    if(l==0) psn[(size_t)h*B_N + r0] = sq0;
    if constexpr(EBF){
      unsigned short* o0 = ebf + (size_t)r0*D_N + d0;
      ushort4 hb;
      hb.x=bfbits(a0.x); hb.y=bfbits(a0.y); hb.z=bfbits(a0.z); hb.w=bfbits(a0.w);
      *(ushort4*)&o0[l*4] = hb;
      hb.x=bfbits(a1.x); hb.y=bfbits(a1.y); hb.z=bfbits(a1.z); hb.w=bfbits(a1.w);
      *(ushort4*)&o0[256 + l*4] = hb;
    }
    acc0[0]+=a0.x; acc0[1]+=a0.y; acc0[2]+=a0.z; acc0[3]+=a0.w;
    acc1[0]+=a1.x; acc1[1]+=a1.y; acc1[2]+=a1.z; acc1[3]+=a1.w;
  }
  __syncthreads();
  *(f32x4*)&red[w*512 + l*4]       = acc0;
  *(f32x4*)&red[w*512 + 256 + l*4] = acc1;
  __syncthreads();
  if(t < 128){
    f32x4 s = *(f32x4*)&red[t*4];
#pragma unroll
    for(int ww=1; ww<4; ww++){
      f32x4 r2 = *(f32x4*)&red[ww*512 + t*4];
      s[0]+=r2[0]; s[1]+=r2[1]; s[2]+=r2[2]; s[3]+=r2[3];
    }
    float ic = 1.f / fmaxf((float)cnt, 1.f);
    s[0]*=ic; s[1]*=ic; s[2]*=ic; s[3]*=ic;
    *(f32x4*)&cent[(size_t)c*D_N + d0 + t*4] = s;
    ushort4 hb;
    hb.x=bfbits(s[0]); hb.y=bfbits(s[1]); hb.z=bfbits(s[2]); hb.w=bfbits(s[3]);
    *(ushort4*)&centnb[(size_t)c*D_N + d0 + t*4] = hb;
  }
}

// ---------------- centroid Gram (k-split 16) + diag -> c2raw atomicAdd ------
__global__ __launch_bounds__(256) void tgl_gram(const float* __restrict__ cent,
                                                float* __restrict__ gramp,
                                                float* __restrict__ c2raw){
  __shared__ float at[64][36];
  __shared__ float bt[64][36];
  int t = threadIdx.x, tx = t & 15, ty = t >> 4;
  int i0 = blockIdx.x*64, j0 = blockIdx.y*64, k0 = blockIdx.z*128;
  float acc[4][4] = {};
  for(int kk=k0; kk<k0+128; kk+=32){
    __syncthreads();
#pragma unroll
    for(int u=0;u<2;u++){
      int v = t + u*256; int r = v>>3, q = (v&7)*4;
      float4 a = (i0+r < C_N) ? *(const float4*)&cent[(size_t)(i0+r)*D_N + kk + q] : make_float4(0,0,0,0);
      *(float4*)&at[r][q] = a;
      float4 b = (j0+r < C_N) ? *(const float4*)&cent[(size_t)(j0+r)*D_N + kk + q] : make_float4(0,0,0,0);
      *(float4*)&bt[r][q] = b;
    }
    __syncthreads();
#pragma unroll
    for(int kq=0;kq<8;kq++){
      float4 a[4], b[4];
#pragma unroll
      for(int i=0;i<4;i++) a[i] = *(float4*)&at[ty*4+i][kq*4];
#pragma unroll
      for(int j=0;j<4;j++) b[j] = *(float4*)&bt[tx+16*j][kq*4];
#pragma unroll
      for(int i=0;i<4;i++)
#pragma unroll
        for(int j=0;j<4;j++)
          acc[i][j] += a[i].x*b[j].x + a[i].y*b[j].y + a[i].z*b[j].z + a[i].w*b[j].w;
    }
  }
  float* slab = gramp + (size_t)blockIdx.z*65536;
#pragma unroll
  for(int i=0;i<4;i++)
#pragma unroll
    for(int j=0;j<4;j++)
      slab[(size_t)(i0+ty*4+i)*CP + (j0+tx+16*j)] = acc[i][j];
  if(i0 == j0){
#pragma unroll
    for(int i=0;i<4;i++)
#pragma unroll
      for(int j=0;j<4;j++)
        if(ty*4+i == tx+16*j && i0+ty*4+i < C_N)
          atomicAdd(&c2raw[i0+ty*4+i], acc[i][j]);
  }
}

// ---------------- margin GEMM: 64x256 tile, 512 thr, 3-buffer counted-vmcnt --
// Epilogue: inv_en inline from psn; cinv/c2n from c2raw (gram diag) — cfin gone.
template<bool EBF>
__global__ __launch_bounds__(512) void tgl_margin(const unsigned short* __restrict__ ebf,
                                                  const float* __restrict__ emb,
                                                  const float* __restrict__ psn,
                                                  const unsigned short* __restrict__ centnb,
                                                  const int* __restrict__ labels,
                                                  const float* __restrict__ c2raw,
                                                  float* __restrict__ pp){
  __shared__ __align__(16) char smem[122880];  // 3 x (A 8KB + B 32KB)
  int t = threadIdx.x, w = t>>6, l = t&63;
  int wm = w>>2, wn = w&3;                     // 8 waves: 2 (M) x 4 (N), 32x64 each
  int s0 = blockIdx.x*64;

  // hoisted per-thread staging sources + LDS byte offsets (advance by kk only)
  const unsigned short* pA;
  const unsigned short* pB[4];
  int ldsA = t*16;
  int ldsB[4];
  {
    int rowA = t>>3, ksA = t&7;
    pA = ebf + (size_t)(s0+rowA)*D_N + ((ksA ^ (rowA&7))<<3);
#pragma unroll
    for(int q=0;q<4;q++){
      int s2 = q*512 + t;
      int rowB = s2>>3, ksB = s2&7;
      pB[q] = centnb + (size_t)rowB*D_N + ((ksB ^ (rowB&7))<<3);
      ldsB[q] = 8192 + s2*16;
    }
  }
  const float* pE[2]; int ldsE[2];
  if constexpr(!EBF){
#pragma unroll
    for(int q2=0;q2<2;q2++){
      int v = q2*512 + t;
      int rowE = v>>4, kqE = v&15;
      pE[q2] = emb + (size_t)(s0+rowE)*D_N + kqE*4;
      ldsE[q2] = rowE*128 + (((kqE>>1)^(rowE&7))<<4) + (kqE&1)*8;
    }
  }

  auto stage = [&](char* dst, int kk){
#pragma unroll
    for(int q=0;q<4;q++)
      gload_lds16(pB[q] + kk, dst + ldsB[q]);
    if constexpr(EBF){
      gload_lds16(pA + kk, dst + ldsA);
    } else {
#pragma unroll
      for(int q2=0;q2<2;q2++){
        float4 f = *(const float4*)(pE[q2] + kk);
        ushort4 hb;
        hb.x=bfbits(f.x); hb.y=bfbits(f.y); hb.z=bfbits(f.z); hb.w=bfbits(f.w);
        *(ushort4*)(dst + ldsE[q2]) = hb;
      }
    }
  };

  // hoisted ds_read byte offsets: A row m at m*128 ^swizzle; B at +8192
  int baseA[2], baseB[4], xofs[2];
#pragma unroll
  for(int i=0;i<2;i++)  baseA[i]  = (wm*32 + i*16 + (l&15))*128;
#pragma unroll
  for(int jj=0;jj<4;jj++) baseB[jj] = 8192 + (wn*64 + jj*16 + (l&15))*128;
#pragma unroll
  for(int s=0;s<2;s++)  xofs[s]  = ((s*4 + (l>>4)) ^ (l&7))<<4;

  char* bR = smem;              // read
  char* bN = smem + 40960;      // next (in flight)
  char* bS = smem + 81920;      // stage target
  f32x4 acc[2][4] = {};

  stage(bR, 0);
  stage(bN, 64);
  if constexpr(EBF) asm volatile("s_waitcnt vmcnt(5)" ::: "memory");
  else              asm volatile("s_waitcnt vmcnt(0) lgkmcnt(0)" ::: "memory");
  __builtin_amdgcn_s_barrier();

  for(int ks=0; ks<32; ++ks){
    if(ks < 30) stage(bS, (ks+2)*64);
#pragma unroll
    for(int s=0;s<2;s++){
      bf16x8 af[2], bfr[4];
#pragma unroll
      for(int i=0;i<2;i++)   af[i]   = *(const bf16x8*)(bR + baseA[i]  + xofs[s]);
#pragma unroll
      for(int jj=0;jj<4;jj++) bfr[jj] = *(const bf16x8*)(bR + baseB[jj] + xofs[s]);
#pragma unroll
      for(int i=0;i<2;i++)
#pragma unroll
        for(int jj=0;jj<4;jj++)
          acc[i][jj] = __builtin_amdgcn_mfma_f32_16x16x32_bf16(af[i], bfr[jj], acc[i][jj], 0,0,0);
    }
    if constexpr(EBF){
      if(ks < 30) asm volatile("s_waitcnt vmcnt(5)" ::: "memory");
      else        asm volatile("s_waitcnt vmcnt(0)" ::: "memory");
    } else {
      asm volatile("s_waitcnt vmcnt(0) lgkmcnt(0)" ::: "memory");
    }
    __builtin_amdgcn_s_barrier();
    char* tmp = bR; bR = bN; bN = bS; bS = tmp;
  }

  float c2nv[4], civ[4];
#pragma unroll
  for(int jj=0;jj<4;jj++){
    int c = wn*64 + jj*16 + (l&15);
    float ss = (c < C_N) ? c2raw[c] : 0.f;
    float cv = 1.f / fmaxf(sqrtf(ss), 1e-12f);
    civ[jj]  = cv;
    c2nv[jj] = ss*cv*cv;
  }
#pragma unroll
  for(int i=0;i<2;i++){
#pragma unroll
    for(int r=0;r<4;r++){
      int srow = s0 + wm*32 + i*16 + (l>>4)*4 + r;
      int lab = labels[srow];
      float sn = psn[srow] + psn[B_N+srow] + psn[2*B_N+srow] + psn[3*B_N+srow];
      float inv = 1.f / fmaxf(sqrtf(sn), 1e-12f);
#pragma unroll
      for(int jj=0;jj<4;jj++){
        int c = wn*64 + jj*16 + (l&15);
        if(c < C_N){
          float dot = acc[i][jj][r]*inv*civ[jj];
          float d2 = 1.f + c2nv[jj] - 2.f*dot;
          float h = 1.2f - sqrtf(fmaxf(d2, 0.f));
          if(h > 0.f) atomicAdd(&pp[(size_t)lab*C_N + c], h);
        }
      }
    }
  }
}

// ---------------- tail2: pdist-reduce + topo (expanded) + margin + finalize --
//   Sum (pd/pmax - M/maxM)^2 = S1/pmax^2 - 2*S2/(pmax*maxM) + S3/maxM^2
// npresent computed here from counts (diagonal threads) — cfin gone.
__global__ __launch_bounds__(256) void tgl_tail2(const float* __restrict__ gramp,
                                                 const float* __restrict__ c2raw,
                                                 const float* __restrict__ counts,
                                                 const float* __restrict__ M,
                                                 const float* __restrict__ pp,
                                                 float* __restrict__ scal,
                                                 float* __restrict__ out){
  unsigned* scal_u = (unsigned*)scal;
  float maxM = scal[3];                 // finalized in fat1 (kernel boundaries ago)
  float inv_maxM = 1.f / maxM;
  int idx = blockIdx.x*256 + threadIdx.x;
  float s1=0.f, s2=0.f, s3=0.f, c1=0.f, sm=0.f, c2=0.f, npv=0.f;
  if(idx < C_N*C_N){
    int i = idx / C_N, j = idx % C_N;
    float g = 0.f;
#pragma unroll
    for(int s=0; s<16; s++) g += gramp[(size_t)s*65536 + (size_t)i*CP + j];
    float ps = c2raw[i] + c2raw[j] - 2.f*g;
    float pd = sqrtf(fmaxf(ps, 0.f) + 1e-12f);
    bool both = counts[i] > 0.f && counts[j] > 0.f;
    if(both) atomicMax(&scal_u[4], __float_as_uint(pd));
    float Mv = M[idx];
    if(j > i && both){ s1 = pd*pd; s2 = pd*Mv; s3 = Mv*Mv; c1 = 1.f; }
    float Mn = Mv*inv_maxM;
    if(i != j && both && Mn < 0.3f){
      sm = pp[idx] / fmaxf(counts[i], 1.f);
      c2 = 1.f;
    }
    if(i == j && counts[i] > 0.f) npv = 1.f;
  }
  s1 = blockSum256(s1); s2 = blockSum256(s2); s3 = blockSum256(s3);
  c1 = blockSum256(c1); sm = blockSum256(sm); c2 = blockSum256(c2);
  npv = blockSum256(npv);
  if(threadIdx.x==0){
    atomicAdd(&scal[1], s1); atomicAdd(&scal[9], s2); atomicAdd(&scal[10], s3);
    atomicAdd(&scal[5], c1); atomicAdd(&scal[2], sm); atomicAdd(&scal[6], c2);
    atomicAdd(&scal[11], npv);
    __threadfence();
    unsigned old = atomicAdd(&scal_u[8], 1u);
    if(old == gridDim.x - 1){
      float S1   = atomicAdd(&scal[1], 0.f);
      float S2b  = atomicAdd(&scal[9], 0.f);
      float S3b  = atomicAdd(&scal[10], 0.f);
      float nu   = atomicAdd(&scal[5], 0.f);
      float msum = atomicAdd(&scal[2], 0.f);
      float np   = atomicAdd(&scal[6], 0.f);
      float nprf = atomicAdd(&scal[11], 0.f);
      float ce   = atomicAdd(&scal[0], 0.f) / (float)B_N;
      float pmax = __uint_as_float(atomicMax(&scal_u[4], 0u));
      float ip = 1.f / pmax;
      float tsum = fmaxf(S1*ip*ip - 2.f*S2b*ip*inv_maxM + S3b*inv_maxM*inv_maxM, 0.f);
      int gate = nprf >= 1.5f;
      float topo   = gate ? tsum / fmaxf(nu, 1.f) : 0.f;
      float margin = (gate && np > 0.f) ? msum / fmaxf(np, 1.f) : 0.f;
      out[0] = ce + 0.1f*topo + 0.05f*margin;
      out[1] = ce;
      out[2] = topo;
      out[3] = margin;
    }
  }
}

extern "C" void kernel_launch(void* const* d_in, const int* in_sizes, int n_in,
                              void* d_out, int out_size, void* d_ws, size_t ws_size,
                              hipStream_t stream){
  const float* logits = (const float*)d_in[0];
  const int*   labels = (const int*)d_in[1];
  const float* emb    = (const float*)d_in[2];
  const float* M      = (const float*)d_in[3];
  float* out = (float*)d_out;
  float* ws  = (float*)d_ws;

  float* pp     = ws + OFF_PP;
  float* scal   = ws + OFF_SCAL;
  float* c2raw  = ws + OFF_C2RAW;
  float* counts = ws + OFF_COUNTS;
  int*   offg   = (int*)(ws + OFF_OFFG);
  int*   bh     = (int*)(ws + OFF_BH);
  int*   sorted = (int*)(ws + OFF_SORT);
  float* cent   = ws + OFF_CENT;
  float* gramp  = ws + OFF_GRAMP;
  float* psn    = ws + OFF_PSN;
  unsigned short* centnb = (unsigned short*)(ws + OFF_CENTNB);
  unsigned short* ebf    = (unsigned short*)(ws + OFF_EBF);

  bool use_ebf = (ws_size / sizeof(float)) >= (size_t)T2_END;

  hipMemsetAsync(d_ws, 0, (size_t)ZERO_N*sizeof(float), stream);

  tgl_cehist<<<1088, 256, 0, stream>>>(logits, labels, M, bh, centnb, scal);
  tgl_scatter<<<64, 256, 0, stream>>>(labels, bh, offg, counts, sorted);
  {
    dim3 g(C_N, 4);
    if(use_ebf) tgl_gather<true ><<<g, 256, 0, stream>>>(emb, sorted, offg, cent, psn, ebf, centnb);
    else        tgl_gather<false><<<g, 256, 0, stream>>>(emb, sorted, offg, cent, psn, ebf, centnb);
  }
  {
    dim3 g(4, 4, 16);
    tgl_gram<<<g, 256, 0, stream>>>(cent, gramp, c2raw);
  }
  {
    if(use_ebf) tgl_margin<true ><<<256, 512, 0, stream>>>(ebf, emb, psn, centnb, labels, c2raw, pp);
    else        tgl_margin<false><<<256, 512, 0, stream>>>(ebf, emb, psn, centnb, labels, c2raw, pp);
  }
  tgl_tail2<<<(C_N*C_N + 255)/256, 256, 0, stream>>>(gramp, c2raw, counts, M, pp, scal, out);
}

// Round 7
// 335.827 us; speedup vs baseline: 1.0153x; 1.0153x over previous
//
#include <hip/hip_runtime.h>
#include <math.h>

#define B_N 16384
#define C_N 250
#define D_N 2048
#define CP  256

// ---- workspace layout (float offsets) ----
// zeroed region (one small hipMemsetAsync):
#define OFF_PP     0          // 62500
#define OFF_SCAL   62500      // 64 (incl tail counter u[8])
#define OFF_C2RAW  62564      // 256 (gram diag atomicAdd target)
#define ZERO_N     62820
// non-zeroed (fully written before read):
#define OFF_COUNTS 62820      // 256
#define OFF_OFFG   63076      // 260 ints (off[257])
#define OFF_BH     63336      // 16384 ints
#define OFF_SORT   79720      // 16384 ints
#define OFF_CENT   96104      // 524288 (mean, fp32)
#define OFF_GRAMP  620392     // 1048576 = 16 slices x 256x256
#define OFF_PSN    1668968    // 65536 = 4 quarters x 16384
#define OFF_CENTNB 1734504    // 262144 floats = 256x2048 bf16 (UNnormalized mean)
#define T1_END     1996648    // ~8 MB
#define OFF_EBF    1996648    // 16777216 floats = 16384x2048 bf16 (UNnormalized)
#define T2_END     18773864   // ~75 MB

// scalar slots: float: 0=ce_sum 1=S1(pd^2) 2=margin_sum 5=n_upper 6=n_pairs
//               9=S2(pd*M) 10=S3(M^2) 11=npresent(float)
// uint: 3=maxM bits, 4=pmax bits, 8=tail counter

typedef __bf16 bf16x8 __attribute__((ext_vector_type(8)));
typedef float  f32x4  __attribute__((ext_vector_type(4)));

__device__ __forceinline__ unsigned short bfbits(float x){
  unsigned u = __float_as_uint(x);
  return (unsigned short)((u + 0x7FFFu + ((u>>16)&1u)) >> 16);  // RNE
}

__device__ __forceinline__ void gload_lds16(const void* g, void* l){
  __builtin_amdgcn_global_load_lds(
      (const __attribute__((address_space(1))) unsigned*)g,
      (__attribute__((address_space(3))) unsigned*)l, 16, 0, 0);
}

__device__ __forceinline__ float warpSum(float v){
#pragma unroll
  for(int o=32;o;o>>=1) v += __shfl_xor(v,o,64);
  return v;
}
__device__ __forceinline__ float warpMax(float v){
#pragma unroll
  for(int o=32;o;o>>=1) v = fmaxf(v, __shfl_xor(v,o,64));
  return v;
}
__device__ __forceinline__ float blockSum256(float v){
  __shared__ float s[4];
  int lane = threadIdx.x & 63, w = threadIdx.x >> 6;
  v = warpSum(v);
  __syncthreads();
  if(lane==0) s[w]=v;
  __syncthreads();
  return s[0]+s[1]+s[2]+s[3];
}
__device__ __forceinline__ float blockMax256(float v){
  __shared__ float s[4];
  int lane = threadIdx.x & 63, w = threadIdx.x >> 6;
  v = warpMax(v);
  __syncthreads();
  if(lane==0) s[w]=v;
  __syncthreads();
  return fmaxf(fmaxf(s[0],s[1]), fmaxf(s[2],s[3]));
}

// ---------------- histM: hist + maxM + centnb pad (64 blocks, load-bearing) --
__global__ __launch_bounds__(256) void tgl_histM(const int* __restrict__ labels,
                                                 const float* __restrict__ M,
                                                 int* __restrict__ bh,
                                                 unsigned short* __restrict__ centnb,
                                                 float* __restrict__ scal){
  __shared__ int h[256];
  unsigned* scal_u = (unsigned*)scal;
  int b = blockIdx.x, t = threadIdx.x;
  h[t] = 0;
  __syncthreads();
  atomicAdd(&h[labels[b*256 + t]], 1);
  __syncthreads();
  bh[b*256 + t] = h[t];
  // fused max(M) chunk (needed by tail2's margin mask)
  float lm = 0.f;
  int i1 = b*977 + 977; if(i1 > C_N*C_N) i1 = C_N*C_N;
  for(int i = b*977 + t; i < i1; i += 256) lm = fmaxf(lm, M[i]);
  lm = blockMax256(lm);
  if(t==0) atomicMax(&scal_u[3], __float_as_uint(lm));
  // centnb bf16 zero-pad rows 250..255 (margin B-staging reads 256 rows)
  if(b < 6){
    for(int d=t; d<D_N; d+=256) centnb[(size_t)(C_N+b)*D_N + d] = 0;
  }
}

// ---------------- scatter2: per-block re-scan of bh + scatter (scan fused) --
__global__ __launch_bounds__(256) void tgl_scatter(const int* __restrict__ labels,
                                                   const int* __restrict__ bh,
                                                   int* __restrict__ offg,
                                                   float* __restrict__ counts,
                                                   int* __restrict__ sorted){
  __shared__ int ps[256];
  __shared__ int lofs[256];
  int t = threadIdx.x, b = blockIdx.x;
  int run = 0, locb = 0;
#pragma unroll
  for(int b2=0;b2<64;b2++){
    int h = bh[b2*256 + t];
    if(b2 < b) locb += h;
    run += h;
  }
  ps[t] = run;
  __syncthreads();
  for(int o=1;o<256;o<<=1){
    int v = (t>=o) ? ps[t-o] : 0;
    __syncthreads();
    ps[t] += v;
    __syncthreads();
  }
  int excl = ps[t] - run;
  if(b==0){
    offg[t] = excl;
    if(t==255) offg[256] = ps[255];
    counts[t] = (float)run;
  }
  lofs[t] = excl + locb;
  __syncthreads();
  int r = b*256 + t;
  int pos = atomicAdd(&lofs[labels[r]], 1);
  sorted[pos] = r;
}

// ---------------- gather+CE: segment sum (x<250) | CE extra blocks (x>=250) --
// CE rides the gather dispatch as independent blocks (1024 units x 16 rows),
// filling scheduler slack instead of serial stream time. Gather path is the
// R6-proven body, unchanged after the early-return branch.
template<bool EBF>
__global__ __launch_bounds__(256) void tgl_gather(const float* __restrict__ emb,
                                                  const int* __restrict__ sorted,
                                                  const int* __restrict__ offg,
                                                  const float* __restrict__ logits,
                                                  const int* __restrict__ labels,
                                                  float* __restrict__ cent,
                                                  float* __restrict__ psn,
                                                  unsigned short* __restrict__ ebf,
                                                  unsigned short* __restrict__ centnb,
                                                  float* __restrict__ scal){
  if(blockIdx.x >= C_N){
    // ---- CE blocks: unit e handles rows e*16 .. e*16+15 ----
    int e = (blockIdx.x - C_N)*4 + blockIdx.y;
    int lane = threadIdx.x & 63, w = threadIdx.x >> 6;
    float lsum = 0.f;
#pragma unroll
    for(int u=0; u<4; ++u){
      int r = e*16 + w*4 + u;
      const float* row = logits + (size_t)r*C_N;
      float x0 = (lane     < C_N) ? row[lane]     : -1e30f;
      float x1 = (lane+64  < C_N) ? row[lane+64]  : -1e30f;
      float x2 = (lane+128 < C_N) ? row[lane+128] : -1e30f;
      float x3 = (lane+192 < C_N) ? row[lane+192] : -1e30f;
      float mx = warpMax(fmaxf(fmaxf(x0,x1), fmaxf(x2,x3)));
      float ex = 0.f;
      if(lane     < C_N) ex += expf(x0-mx);
      if(lane+64  < C_N) ex += expf(x1-mx);
      if(lane+128 < C_N) ex += expf(x2-mx);
      if(lane+192 < C_N) ex += expf(x3-mx);
      ex = warpSum(ex);
      if(lane==0){
        int l = labels[r];
        lsum += -(row[l] - mx - logf(ex));
      }
    }
    float tot = blockSum256(lsum);
    if(threadIdx.x==0) atomicAdd(&scal[0], tot);
    return;
  }
  __shared__ float red[2048];            // 8 KB
  int t = threadIdx.x, l = t & 63, w = t >> 6;
  int c = blockIdx.x, h = blockIdx.y;
  int d0 = h*512;
  int off = offg[c];
  int cnt = offg[c+1] - off;
  const int* rows = sorted + off;
  f32x4 acc0 = {}, acc1 = {};
  int k = w;
  for(; k+12 < cnt; k += 16){
    int r0 = rows[k], r1 = rows[k+4], r2 = rows[k+8], r3 = rows[k+12];
    const float* p0 = emb + (size_t)r0*D_N + d0;
    const float* p1 = emb + (size_t)r1*D_N + d0;
    const float* p2 = emb + (size_t)r2*D_N + d0;
    const float* p3 = emb + (size_t)r3*D_N + d0;
    float4 a0 = *(const float4*)&p0[l*4];
    float4 a1 = *(const float4*)&p0[256 + l*4];
    float4 b0 = *(const float4*)&p1[l*4];
    float4 b1 = *(const float4*)&p1[256 + l*4];
    float4 c0 = *(const float4*)&p2[l*4];
    float4 c1 = *(const float4*)&p2[256 + l*4];
    float4 e0 = *(const float4*)&p3[l*4];
    float4 e1 = *(const float4*)&p3[256 + l*4];
    float sq0 = a0.x*a0.x+a0.y*a0.y+a0.z*a0.z+a0.w*a0.w
              + a1.x*a1.x+a1.y*a1.y+a1.z*a1.z+a1.w*a1.w;
    float sq1 = b0.x*b0.x+b0.y*b0.y+b0.z*b0.z+b0.w*b0.w
              + b1.x*b1.x+b1.y*b1.y+b1.z*b1.z+b1.w*b1.w;
    float sq2 = c0.x*c0.x+c0.y*c0.y+c0.z*c0.z+c0.w*c0.w
              + c1.x*c1.x+c1.y*c1.y+c1.z*c1.z+c1.w*c1.w;
    float sq3 = e0.x*e0.x+e0.y*e0.y+e0.z*e0.z+e0.w*e0.w
              + e1.x*e1.x+e1.y*e1.y+e1.z*e1.z+e1.w*e1.w;
    sq0 = warpSum(sq0); sq1 = warpSum(sq1); sq2 = warpSum(sq2); sq3 = warpSum(sq3);
    if(l==0){
      psn[(size_t)h*B_N + r0] = sq0;
      psn[(size_t)h*B_N + r1] = sq1;
      psn[(size_t)h*B_N + r2] = sq2;
      psn[(size_t)h*B_N + r3] = sq3;
    }
    if constexpr(EBF){
      unsigned short* o0 = ebf + (size_t)r0*D_N + d0;
      unsigned short* o1 = ebf + (size_t)r1*D_N + d0;
      unsigned short* o2 = ebf + (size_t)r2*D_N + d0;
      unsigned short* o3 = ebf + (size_t)r3*D_N + d0;
      ushort4 hb;
      hb.x=bfbits(a0.x); hb.y=bfbits(a0.y); hb.z=bfbits(a0.z); hb.w=bfbits(a0.w);
      *(ushort4*)&o0[l*4] = hb;
      hb.x=bfbits(a1.x); hb.y=bfbits(a1.y); hb.z=bfbits(a1.z); hb.w=bfbits(a1.w);
      *(ushort4*)&o0[256 + l*4] = hb;
      hb.x=bfbits(b0.x); hb.y=bfbits(b0.y); hb.z=bfbits(b0.z); hb.w=bfbits(b0.w);
      *(ushort4*)&o1[l*4] = hb;
      hb.x=bfbits(b1.x); hb.y=bfbits(b1.y); hb.z=bfbits(b1.z); hb.w=bfbits(b1.w);
      *(ushort4*)&o1[256 + l*4] = hb;
      hb.x=bfbits(c0.x); hb.y=bfbits(c0.y); hb.z=bfbits(c0.z); hb.w=bfbits(c0.w);
      *(ushort4*)&o2[l*4] = hb;
      hb.x=bfbits(c1.x); hb.y=bfbits(c1.y); hb.z=bfbits(c1.z); hb.w=bfbits(c1.w);
      *(ushort4*)&o2[256 + l*4] = hb;
      hb.x=bfbits(e0.x); hb.y=bfbits(e0.y); hb.z=bfbits(e0.z); hb.w=bfbits(e0.w);
      *(ushort4*)&o3[l*4] = hb;
      hb.x=bfbits(e1.x); hb.y=bfbits(e1.y); hb.z=bfbits(e1.z); hb.w=bfbits(e1.w);
      *(ushort4*)&o3[256 + l*4] = hb;
    }
    acc0[0]+=a0.x+b0.x+c0.x+e0.x; acc0[1]+=a0.y+b0.y+c0.y+e0.y;
    acc0[2]+=a0.z+b0.z+c0.z+e0.z; acc0[3]+=a0.w+b0.w+c0.w+e0.w;
    acc1[0]+=a1.x+b1.x+c1.x+e1.x; acc1[1]+=a1.y+b1.y+c1.y+e1.y;
    acc1[2]+=a1.z+b1.z+c1.z+e1.z; acc1[3]+=a1.w+b1.w+c1.w+e1.w;
  }
  for(; k < cnt; k += 4){
    int r0 = rows[k];
    const float* p0 = emb + (size_t)r0*D_N + d0;
    float4 a0 = *(const float4*)&p0[l*4];
    float4 a1 = *(const float4*)&p0[256 + l*4];
    float sq0 = a0.x*a0.x+a0.y*a0.y+a0.z*a0.z+a0.w*a0.w
              + a1.x*a1.x+a1.y*a1.y+a1.z*a1.z+a1.w*a1.w;
    sq0 = warpSum(sq0);
    if(l==0) psn[(size_t)h*B_N + r0] = sq0;
    if constexpr(EBF){
      unsigned short* o0 = ebf + (size_t)r0*D_N + d0;
      ushort4 hb;
      hb.x=bfbits(a0.x); hb.y=bfbits(a0.y); hb.z=bfbits(a0.z); hb.w=bfbits(a0.w);
      *(ushort4*)&o0[l*4] = hb;
      hb.x=bfbits(a1.x); hb.y=bfbits(a1.y); hb.z=bfbits(a1.z); hb.w=bfbits(a1.w);
      *(ushort4*)&o0[256 + l*4] = hb;
    }
    acc0[0]+=a0.x; acc0[1]+=a0.y; acc0[2]+=a0.z; acc0[3]+=a0.w;
    acc1[0]+=a1.x; acc1[1]+=a1.y; acc1[2]+=a1.z; acc1[3]+=a1.w;
  }
  __syncthreads();
  *(f32x4*)&red[w*512 + l*4]       = acc0;
  *(f32x4*)&red[w*512 + 256 + l*4] = acc1;
  __syncthreads();
  if(t < 128){
    f32x4 s = *(f32x4*)&red[t*4];
#pragma unroll
    for(int ww=1; ww<4; ww++){
      f32x4 r2 = *(f32x4*)&red[ww*512 + t*4];
      s[0]+=r2[0]; s[1]+=r2[1]; s[2]+=r2[2]; s[3]+=r2[3];
    }
    float ic = 1.f / fmaxf((float)cnt, 1.f);
    s[0]*=ic; s[1]*=ic; s[2]*=ic; s[3]*=ic;
    *(f32x4*)&cent[(size_t)c*D_N + d0 + t*4] = s;
    ushort4 hb;
    hb.x=bfbits(s[0]); hb.y=bfbits(s[1]); hb.z=bfbits(s[2]); hb.w=bfbits(s[3]);
    *(ushort4*)&centnb[(size_t)c*D_N + d0 + t*4] = hb;
  }
}

// ---------------- centroid Gram (k-split 16) + diag -> c2raw atomicAdd ------
__global__ __launch_bounds__(256) void tgl_gram(const float* __restrict__ cent,
                                                float* __restrict__ gramp,
                                                float* __restrict__ c2raw){
  __shared__ float at[64][36];
  __shared__ float bt[64][36];
  int t = threadIdx.x, tx = t & 15, ty = t >> 4;
  int i0 = blockIdx.x*64, j0 = blockIdx.y*64, k0 = blockIdx.z*128;
  float acc[4][4] = {};
  for(int kk=k0; kk<k0+128; kk+=32){
    __syncthreads();
#pragma unroll
    for(int u=0;u<2;u++){
      int v = t + u*256; int r = v>>3, q = (v&7)*4;
      float4 a = (i0+r < C_N) ? *(const float4*)&cent[(size_t)(i0+r)*D_N + kk + q] : make_float4(0,0,0,0);
      *(float4*)&at[r][q] = a;
      float4 b = (j0+r < C_N) ? *(const float4*)&cent[(size_t)(j0+r)*D_N + kk + q] : make_float4(0,0,0,0);
      *(float4*)&bt[r][q] = b;
    }
    __syncthreads();
#pragma unroll
    for(int kq=0;kq<8;kq++){
      float4 a[4], b[4];
#pragma unroll
      for(int i=0;i<4;i++) a[i] = *(float4*)&at[ty*4+i][kq*4];
#pragma unroll
      for(int j=0;j<4;j++) b[j] = *(float4*)&bt[tx+16*j][kq*4];
#pragma unroll
      for(int i=0;i<4;i++)
#pragma unroll
        for(int j=0;j<4;j++)
          acc[i][j] += a[i].x*b[j].x + a[i].y*b[j].y + a[i].z*b[j].z + a[i].w*b[j].w;
    }
  }
  float* slab = gramp + (size_t)blockIdx.z*65536;
#pragma unroll
  for(int i=0;i<4;i++)
#pragma unroll
    for(int j=0;j<4;j++)
      slab[(size_t)(i0+ty*4+i)*CP + (j0+tx+16*j)] = acc[i][j];
  if(i0 == j0){
#pragma unroll
    for(int i=0;i<4;i++)
#pragma unroll
      for(int j=0;j<4;j++)
        if(ty*4+i == tx+16*j && i0+ty*4+i < C_N)
          atomicAdd(&c2raw[i0+ty*4+i], acc[i][j]);
  }
}

// ---------------- margin GEMM: 64x256 tile, 512 thr, 3-buffer counted-vmcnt --
// Epilogue: inv_en inline from psn; cinv/c2n from c2raw (gram diag).
template<bool EBF>
__global__ __launch_bounds__(512) void tgl_margin(const unsigned short* __restrict__ ebf,
                                                  const float* __restrict__ emb,
                                                  const float* __restrict__ psn,
                                                  const unsigned short* __restrict__ centnb,
                                                  const int* __restrict__ labels,
                                                  const float* __restrict__ c2raw,
                                                  float* __restrict__ pp){
  __shared__ __align__(16) char smem[122880];  // 3 x (A 8KB + B 32KB)
  int t = threadIdx.x, w = t>>6, l = t&63;
  int wm = w>>2, wn = w&3;                     // 8 waves: 2 (M) x 4 (N), 32x64 each
  int s0 = blockIdx.x*64;

  // hoisted per-thread staging sources + LDS byte offsets (advance by kk only)
  const unsigned short* pA;
  const unsigned short* pB[4];
  int ldsA = t*16;
  int ldsB[4];
  {
    int rowA = t>>3, ksA = t&7;
    pA = ebf + (size_t)(s0+rowA)*D_N + ((ksA ^ (rowA&7))<<3);
#pragma unroll
    for(int q=0;q<4;q++){
      int s2 = q*512 + t;
      int rowB = s2>>3, ksB = s2&7;
      pB[q] = centnb + (size_t)rowB*D_N + ((ksB ^ (rowB&7))<<3);
      ldsB[q] = 8192 + s2*16;
    }
  }
  const float* pE[2]; int ldsE[2];
  if constexpr(!EBF){
#pragma unroll
    for(int q2=0;q2<2;q2++){
      int v = q2*512 + t;
      int rowE = v>>4, kqE = v&15;
      pE[q2] = emb + (size_t)(s0+rowE)*D_N + kqE*4;
      ldsE[q2] = rowE*128 + (((kqE>>1)^(rowE&7))<<4) + (kqE&1)*8;
    }
  }

  auto stage = [&](char* dst, int kk){
#pragma unroll
    for(int q=0;q<4;q++)
      gload_lds16(pB[q] + kk, dst + ldsB[q]);
    if constexpr(EBF){
      gload_lds16(pA + kk, dst + ldsA);
    } else {
#pragma unroll
      for(int q2=0;q2<2;q2++){
        float4 f = *(const float4*)(pE[q2] + kk);
        ushort4 hb;
        hb.x=bfbits(f.x); hb.y=bfbits(f.y); hb.z=bfbits(f.z); hb.w=bfbits(f.w);
        *(ushort4*)(dst + ldsE[q2]) = hb;
      }
    }
  };

  // hoisted ds_read byte offsets: A row m at m*128 ^swizzle; B at +8192
  int baseA[2], baseB[4], xofs[2];
#pragma unroll
  for(int i=0;i<2;i++)  baseA[i]  = (wm*32 + i*16 + (l&15))*128;
#pragma unroll
  for(int jj=0;jj<4;jj++) baseB[jj] = 8192 + (wn*64 + jj*16 + (l&15))*128;
#pragma unroll
  for(int s=0;s<2;s++)  xofs[s]  = ((s*4 + (l>>4)) ^ (l&7))<<4;

  char* bR = smem;              // read
  char* bN = smem + 40960;      // next (in flight)
  char* bS = smem + 81920;      // stage target
  f32x4 acc[2][4] = {};

  stage(bR, 0);
  stage(bN, 64);
  if constexpr(EBF) asm volatile("s_waitcnt vmcnt(5)" ::: "memory");
  else              asm volatile("s_waitcnt vmcnt(0) lgkmcnt(0)" ::: "memory");
  __builtin_amdgcn_s_barrier();

  for(int ks=0; ks<32; ++ks){
    if(ks < 30) stage(bS, (ks+2)*64);
#pragma unroll
    for(int s=0;s<2;s++){
      bf16x8 af[2], bfr[4];
#pragma unroll
      for(int i=0;i<2;i++)   af[i]   = *(const bf16x8*)(bR + baseA[i]  + xofs[s]);
#pragma unroll
      for(int jj=0;jj<4;jj++) bfr[jj] = *(const bf16x8*)(bR + baseB[jj] + xofs[s]);
#pragma unroll
      for(int i=0;i<2;i++)
#pragma unroll
        for(int jj=0;jj<4;jj++)
          acc[i][jj] = __builtin_amdgcn_mfma_f32_16x16x32_bf16(af[i], bfr[jj], acc[i][jj], 0,0,0);
    }
    if constexpr(EBF){
      if(ks < 30) asm volatile("s_waitcnt vmcnt(5)" ::: "memory");
      else        asm volatile("s_waitcnt vmcnt(0)" ::: "memory");
    } else {
      asm volatile("s_waitcnt vmcnt(0) lgkmcnt(0)" ::: "memory");
    }
    __builtin_amdgcn_s_barrier();
    char* tmp = bR; bR = bN; bN = bS; bS = tmp;
  }

  float c2nv[4], civ[4];
#pragma unroll
  for(int jj=0;jj<4;jj++){
    int c = wn*64 + jj*16 + (l&15);
    float ss = (c < C_N) ? c2raw[c] : 0.f;
    float cv = 1.f / fmaxf(sqrtf(ss), 1e-12f);
    civ[jj]  = cv;
    c2nv[jj] = ss*cv*cv;
  }
#pragma unroll
  for(int i=0;i<2;i++){
#pragma unroll
    for(int r=0;r<4;r++){
      int srow = s0 + wm*32 + i*16 + (l>>4)*4 + r;
      int lab = labels[srow];
      float sn = psn[srow] + psn[B_N+srow] + psn[2*B_N+srow] + psn[3*B_N+srow];
      float inv = 1.f / fmaxf(sqrtf(sn), 1e-12f);
#pragma unroll
      for(int jj=0;jj<4;jj++){
        int c = wn*64 + jj*16 + (l&15);
        if(c < C_N){
          float dot = acc[i][jj][r]*inv*civ[jj];
          float d2 = 1.f + c2nv[jj] - 2.f*dot;
          float h = 1.2f - sqrtf(fmaxf(d2, 0.f));
          if(h > 0.f) atomicAdd(&pp[(size_t)lab*C_N + c], h);
        }
      }
    }
  }
}

// ---------------- tail2: pdist-reduce + topo (expanded) + margin + finalize --
//   Sum (pd/pmax - M/maxM)^2 = S1/pmax^2 - 2*S2/(pmax*maxM) + S3/maxM^2
__global__ __launch_bounds__(256) void tgl_tail2(const float* __restrict__ gramp,
                                                 const float* __restrict__ c2raw,
                                                 const float* __restrict__ counts,
                                                 const float* __restrict__ M,
                                                 const float* __restrict__ pp,
                                                 float* __restrict__ scal,
                                                 float* __restrict__ out){
  unsigned* scal_u = (unsigned*)scal;
  float maxM = scal[3];                 // finalized in histM (kernel boundaries ago)
  float inv_maxM = 1.f / maxM;
  int idx = blockIdx.x*256 + threadIdx.x;
  float s1=0.f, s2=0.f, s3=0.f, c1=0.f, sm=0.f, c2=0.f, npv=0.f;
  if(idx < C_N*C_N){
    int i = idx / C_N, j = idx % C_N;
    float g = 0.f;
#pragma unroll
    for(int s=0; s<16; s++) g += gramp[(size_t)s*65536 + (size_t)i*CP + j];
    float ps = c2raw[i] + c2raw[j] - 2.f*g;
    float pd = sqrtf(fmaxf(ps, 0.f) + 1e-12f);
    bool both = counts[i] > 0.f && counts[j] > 0.f;
    if(both) atomicMax(&scal_u[4], __float_as_uint(pd));
    float Mv = M[idx];
    if(j > i && both){ s1 = pd*pd; s2 = pd*Mv; s3 = Mv*Mv; c1 = 1.f; }
    float Mn = Mv*inv_maxM;
    if(i != j && both && Mn < 0.3f){
      sm = pp[idx] / fmaxf(counts[i], 1.f);
      c2 = 1.f;
    }
    if(i == j && counts[i] > 0.f) npv = 1.f;
  }
  s1 = blockSum256(s1); s2 = blockSum256(s2); s3 = blockSum256(s3);
  c1 = blockSum256(c1); sm = blockSum256(sm); c2 = blockSum256(c2);
  npv = blockSum256(npv);
  if(threadIdx.x==0){
    atomicAdd(&scal[1], s1); atomicAdd(&scal[9], s2); atomicAdd(&scal[10], s3);
    atomicAdd(&scal[5], c1); atomicAdd(&scal[2], sm); atomicAdd(&scal[6], c2);
    atomicAdd(&scal[11], npv);
    __threadfence();
    unsigned old = atomicAdd(&scal_u[8], 1u);
    if(old == gridDim.x - 1){
      float S1   = atomicAdd(&scal[1], 0.f);
      float S2b  = atomicAdd(&scal[9], 0.f);
      float S3b  = atomicAdd(&scal[10], 0.f);
      float nu   = atomicAdd(&scal[5], 0.f);
      float msum = atomicAdd(&scal[2], 0.f);
      float np   = atomicAdd(&scal[6], 0.f);
      float nprf = atomicAdd(&scal[11], 0.f);
      float ce   = atomicAdd(&scal[0], 0.f) / (float)B_N;
      float pmax = __uint_as_float(atomicMax(&scal_u[4], 0u));
      float ip = 1.f / pmax;
      float tsum = fmaxf(S1*ip*ip - 2.f*S2b*ip*inv_maxM + S3b*inv_maxM*inv_maxM, 0.f);
      int gate = nprf >= 1.5f;
      float topo   = gate ? tsum / fmaxf(nu, 1.f) : 0.f;
      float margin = (gate && np > 0.f) ? msum / fmaxf(np, 1.f) : 0.f;
      out[0] = ce + 0.1f*topo + 0.05f*margin;
      out[1] = ce;
      out[2] = topo;
      out[3] = margin;
    }
  }
}

extern "C" void kernel_launch(void* const* d_in, const int* in_sizes, int n_in,
                              void* d_out, int out_size, void* d_ws, size_t ws_size,
                              hipStream_t stream){
  const float* logits = (const float*)d_in[0];
  const int*   labels = (const int*)d_in[1];
  const float* emb    = (const float*)d_in[2];
  const float* M      = (const float*)d_in[3];
  float* out = (float*)d_out;
  float* ws  = (float*)d_ws;

  float* pp     = ws + OFF_PP;
  float* scal   = ws + OFF_SCAL;
  float* c2raw  = ws + OFF_C2RAW;
  float* counts = ws + OFF_COUNTS;
  int*   offg   = (int*)(ws + OFF_OFFG);
  int*   bh     = (int*)(ws + OFF_BH);
  int*   sorted = (int*)(ws + OFF_SORT);
  float* cent   = ws + OFF_CENT;
  float* gramp  = ws + OFF_GRAMP;
  float* psn    = ws + OFF_PSN;
  unsigned short* centnb = (unsigned short*)(ws + OFF_CENTNB);
  unsigned short* ebf    = (unsigned short*)(ws + OFF_EBF);

  bool use_ebf = (ws_size / sizeof(float)) >= (size_t)T2_END;

  hipMemsetAsync(d_ws, 0, (size_t)ZERO_N*sizeof(float), stream);

  tgl_histM<<<64, 256, 0, stream>>>(labels, M, bh, centnb, scal);
  tgl_scatter<<<64, 256, 0, stream>>>(labels, bh, offg, counts, sorted);
  {
    dim3 g(C_N + 256, 4);   // x<250: gather; x>=250: CE (1024 units x 16 rows)
    if(use_ebf) tgl_gather<true ><<<g, 256, 0, stream>>>(emb, sorted, offg, logits, labels, cent, psn, ebf, centnb, scal);
    else        tgl_gather<false><<<g, 256, 0, stream>>>(emb, sorted, offg, logits, labels, cent, psn, ebf, centnb, scal);
  }
  {
    dim3 g(4, 4, 16);
    tgl_gram<<<g, 256, 0, stream>>>(cent, gramp, c2raw);
  }
  {
    if(use_ebf) tgl_margin<true ><<<256, 512, 0, stream>>>(ebf, emb, psn, centnb, labels, c2raw, pp);
    else        tgl_margin<false><<<256, 512, 0, stream>>>(ebf, emb, psn, centnb, labels, c2raw, pp);
  }
  tgl_tail2<<<(C_N*C_N + 255)/256, 256, 0, stream>>>(gramp, c2raw, counts, M, pp, scal, out);
}